// Round 1
// baseline (287.063 us; speedup 1.0000x reference)
//
#include <hip/hip_runtime.h>
#include <hip/hip_bf16.h>

// NT-Xent (B=8192, D=128): fused flash-style lse over e=exp(sim/T).
// K1: L2-normalize -> bf16 reps[16384][128] in ws; zero d_out.
// K2: grid (128 row-blocks x 4 col-splits); per block: MFMA 128x128 tiles,
//     online logsumexp over e-values; per-(row,split) partials {m,s,pos} to ws.
// K3: combine 4 splits per row, lse = m + log(s), reduce mean(lse - pos) -> d_out.

#define NROWS 16384
#define BHALF 8192
#define DDIM  128
#define TILE  128
#define NSPLIT 4
#define COLS_PER_SPLIT (NROWS / NSPLIT)   // 4096
#define NITERS (COLS_PER_SPLIT / TILE)    // 32
#define LDS_STRIDE 136                    // bf16 elems: +8 pad -> 2-way bank alias (free)
#define LOG2E 1.4426950408889634f
#define C_EXP (LOG2E / 0.07f)             // exp(sim/T) = exp2(dot * C_EXP)

typedef __attribute__((ext_vector_type(8))) short bf16x8;
typedef __attribute__((ext_vector_type(4))) float f32x4;

__device__ inline unsigned short f2bf(float x) {
    unsigned int b = __float_as_uint(x);
    b += 0x7FFFu + ((b >> 16) & 1u);
    return (unsigned short)(b >> 16);
}

// ---------------- Kernel A: normalize rows -> bf16 reps; zero out ----------------
__global__ void norm_kernel(const float* __restrict__ zi, const float* __restrict__ zj,
                            unsigned short* __restrict__ reps, float* __restrict__ out) {
    int w = threadIdx.x >> 6;
    int lane = threadIdx.x & 63;
    int row = blockIdx.x * 4 + w;                       // 4096 blocks x 4 rows
    const float* src = (row < BHALF) ? (zi + (size_t)row * DDIM)
                                     : (zj + (size_t)(row - BHALF) * DDIM);
    float2 v = ((const float2*)src)[lane];
    float ss = v.x * v.x + v.y * v.y;
    #pragma unroll
    for (int d = 1; d < 64; d <<= 1) ss += __shfl_xor(ss, d, 64);
    float inv = 1.0f / fmaxf(sqrtf(ss), 1e-12f);
    unsigned int packed = (unsigned int)f2bf(v.x * inv) | ((unsigned int)f2bf(v.y * inv) << 16);
    ((unsigned int*)reps)[(size_t)row * (DDIM / 2) + lane] = packed;
    if (blockIdx.x == 0 && threadIdx.x == 0) out[0] = 0.0f;
}

// ---------------- Kernel B: fused GEMM + online double-exp logsumexp ----------------
__global__ __launch_bounds__(256, 2)
void ntx_main(const unsigned short* __restrict__ reps, float4* __restrict__ part) {
    __shared__ unsigned short lds[TILE * LDS_STRIDE];   // 34816 B
    const int tid = threadIdx.x;
    const int w = tid >> 6, lane = tid & 63;
    const int laneLo = lane & 15, quad = lane >> 4;
    const int bx = blockIdx.x, by = blockIdx.y;
    const int rowBase = bx * TILE + w * 32;             // wave owns 32 rows x 128 cols

    // A fragments (this wave's 32 rows x K=128), loaded once from global.
    // A-frag layout (16x16x32): m = lane&15, k = (lane>>4)*8 + j  -> 16B contiguous
    bf16x8 afrag[2][4];
    #pragma unroll
    for (int rt = 0; rt < 2; ++rt)
        #pragma unroll
        for (int kt = 0; kt < 4; ++kt) {
            int r = rowBase + rt * 16 + laneLo;
            int k = kt * 32 + quad * 8;
            afrag[rt][kt] = *(const bf16x8*)(reps + (size_t)r * DDIM + k);
        }

    // Per-lane online state: rows (rt,rg) -> row = rowBase + rt*16 + quad*4 + rg
    float mst[2][4], sst[2][4], pst[2][4];
    int grow[2][4], pcol[2][4];
    #pragma unroll
    for (int rt = 0; rt < 2; ++rt)
        #pragma unroll
        for (int rg = 0; rg < 4; ++rg) {
            mst[rt][rg] = -__builtin_inff(); sst[rt][rg] = 0.0f; pst[rt][rg] = 0.0f;
            int gr = rowBase + rt * 16 + quad * 4 + rg;
            grow[rt][rg] = gr;
            pcol[rt][rg] = (gr < BHALF) ? gr + BHALF : gr - BHALF;
        }

    const int colBase0 = by * COLS_PER_SPLIT;
    const uint4* repsV = (const uint4*)reps;            // 16 uint4 per row

    for (int it = 0; it < NITERS; ++it) {
        int colBase = colBase0 + it * TILE;
        __syncthreads();
        // stage B tile: rows [colBase, +128) of reps, row-major, padded stride
        #pragma unroll
        for (int i = 0; i < 8; ++i) {
            int idx = tid + i * 256;
            int r = idx >> 4, c = idx & 15;
            uint4 v = repsV[(size_t)(colBase + r) * 16 + c];
            *(uint4*)(&lds[r * LDS_STRIDE + c * 8]) = v;
        }
        __syncthreads();

        f32x4 acc[2][8];
        #pragma unroll
        for (int rt = 0; rt < 2; ++rt)
            #pragma unroll
            for (int c8 = 0; c8 < 8; ++c8) acc[rt][c8] = (f32x4){0.f, 0.f, 0.f, 0.f};

        #pragma unroll
        for (int c8 = 0; c8 < 8; ++c8) {
            bf16x8 bfrag[4];
            int brow = c8 * 16 + laneLo;                // B = R^T -> same frag pattern as A
            #pragma unroll
            for (int kt = 0; kt < 4; ++kt)
                bfrag[kt] = *(const bf16x8*)(&lds[brow * LDS_STRIDE + kt * 32 + quad * 8]);
            #pragma unroll
            for (int rt = 0; rt < 2; ++rt)
                #pragma unroll
                for (int kt = 0; kt < 4; ++kt)
                    acc[rt][c8] = __builtin_amdgcn_mfma_f32_16x16x32_bf16(
                        afrag[rt][kt], bfrag[kt], acc[rt][c8], 0, 0, 0);
        }

        // Epilogue: C/D layout col = lane&15, row = quad*4 + rg
        #pragma unroll
        for (int rt = 0; rt < 2; ++rt)
            #pragma unroll
            for (int rg = 0; rg < 4; ++rg) {
                int gr = grow[rt][rg], pc = pcol[rt][rg];
                float ev[8];
                float lm = -__builtin_inff();
                #pragma unroll
                for (int c8 = 0; c8 < 8; ++c8) {
                    int gc = colBase + c8 * 16 + laneLo;
                    float e = exp2f(acc[rt][c8][rg] * C_EXP);   // e = exp(sim/T)
                    pst[rt][rg] += (gc == pc) ? e : 0.0f;       // positive logit capture
                    e = (gc == gr) ? -__builtin_inff() : e;     // mask diagonal
                    ev[c8] = e;
                    lm = fmaxf(lm, e);
                }
                float mo = mst[rt][rg];
                float mn = fmaxf(mo, lm);
                float s = sst[rt][rg] * exp2f((mo - mn) * LOG2E); // 0*0 on first iter
                #pragma unroll
                for (int c8 = 0; c8 < 8; ++c8) s += exp2f((ev[c8] - mn) * LOG2E);
                mst[rt][rg] = mn; sst[rt][rg] = s;
            }
    }

    // Merge (m,s,pos) across the 16 lanes sharing each row; write partials
    #pragma unroll
    for (int rt = 0; rt < 2; ++rt)
        #pragma unroll
        for (int rg = 0; rg < 4; ++rg) {
            float m = mst[rt][rg], s = sst[rt][rg], p = pst[rt][rg];
            #pragma unroll
            for (int d = 1; d < 16; d <<= 1) {
                float mo = __shfl_xor(m, d, 64);
                float so = __shfl_xor(s, d, 64);
                float po = __shfl_xor(p, d, 64);
                float mn = fmaxf(m, mo);
                s = s * exp2f((m - mn) * LOG2E) + so * exp2f((mo - mn) * LOG2E);
                m = mn; p += po;
            }
            if (laneLo == 0)
                part[(size_t)grow[rt][rg] * NSPLIT + by] = make_float4(m, s, p, 0.0f);
        }
}

// ---------------- Kernel C: combine splits, mean(lse - pos) ----------------
__global__ void finish_kernel(const float4* __restrict__ part, float* __restrict__ out) {
    int row = blockIdx.x * 256 + threadIdx.x;           // 64 blocks x 256
    float4 p0 = part[(size_t)row * NSPLIT + 0];
    float4 p1 = part[(size_t)row * NSPLIT + 1];
    float4 p2 = part[(size_t)row * NSPLIT + 2];
    float4 p3 = part[(size_t)row * NSPLIT + 3];
    float M = fmaxf(fmaxf(p0.x, p1.x), fmaxf(p2.x, p3.x));
    float S = p0.y * exp2f((p0.x - M) * LOG2E) + p1.y * exp2f((p1.x - M) * LOG2E)
            + p2.y * exp2f((p2.x - M) * LOG2E) + p3.y * exp2f((p3.x - M) * LOG2E);
    float P = p0.z + p1.z + p2.z + p3.z;
    float v = (M + logf(S)) - P;                        // lse - pos for this row
    #pragma unroll
    for (int d = 1; d < 64; d <<= 1) v += __shfl_xor(v, d, 64);
    __shared__ float red[4];
    int lane = threadIdx.x & 63, w = threadIdx.x >> 6;
    if (lane == 0) red[w] = v;
    __syncthreads();
    if (threadIdx.x == 0)
        atomicAdd(out, (red[0] + red[1] + red[2] + red[3]) * (1.0f / NROWS));
}

extern "C" void kernel_launch(void* const* d_in, const int* in_sizes, int n_in,
                              void* d_out, int out_size, void* d_ws, size_t ws_size,
                              hipStream_t stream) {
    const float* zi = (const float*)d_in[0];
    const float* zj = (const float*)d_in[1];
    float* out = (float*)d_out;
    unsigned short* reps = (unsigned short*)d_ws;                         // 4 MiB
    float4* part = (float4*)((char*)d_ws + (size_t)NROWS * DDIM * 2);     // +1 MiB

    norm_kernel<<<NROWS / 4, 256, 0, stream>>>(zi, zj, reps, out);
    ntx_main<<<dim3(NROWS / TILE, NSPLIT), 256, 0, stream>>>(reps, part);
    finish_kernel<<<NROWS / 256, 256, 0, stream>>>(part, out);
}

// Round 2
// 250.956 us; speedup vs baseline: 1.1439x; 1.1439x over previous
//
#include <hip/hip_runtime.h>
#include <hip/hip_bf16.h>

// NT-Xent (B=8192, D=128), fused flash-style lse over e=exp(sim/T).
// K1: L2-normalize -> bf16 repsB[16384][128]; also repsA = repsB * (log2e/T)
//     so MFMA(A=repsA, B=repsB^T) yields a = sim*log2e/T directly; zero d_out.
// K2: grid (128 row-blocks x 8 col-splits, 4 blocks/CU); per 128x128 tile:
//     MFMA -> a-values; mask diag to -inf; online max/sum of e=exp2(a) in
//     log2 domain with raw v_exp_f32; per-(row,split) {m,s} partials.
// K3: per row: pos = exp(dot(r_i,r_pos)/T) via direct bf16 dot; combine 8
//     partials; mean(m+log(S) - pos) -> atomicAdd into d_out.

#define NROWS 16384
#define BHALF 8192
#define DDIM  128
#define TILE  128
#define NSPLIT 8
#define COLS_PER_SPLIT (NROWS / NSPLIT)   // 2048
#define NITERS (COLS_PER_SPLIT / TILE)    // 16
#define LDS_STRIDE 136                    // bf16: +8 pad, keeps 16B alignment
#define LOG2E 1.4426950408889634f
#define C_EXP (LOG2E / 0.07f)

typedef __attribute__((ext_vector_type(8))) short bf16x8;
typedef __attribute__((ext_vector_type(4))) float f32x4;

__device__ inline unsigned short f2bf(float x) {
    unsigned int b = __float_as_uint(x);
    b += 0x7FFFu + ((b >> 16) & 1u);
    return (unsigned short)(b >> 16);
}
__device__ inline float bflo(unsigned int u) { return __uint_as_float(u << 16); }
__device__ inline float bfhi(unsigned int u) { return __uint_as_float(u & 0xFFFF0000u); }

// ---------------- K1: normalize -> repsB (unit) + repsA (unit * C_EXP) ----------------
__global__ void norm_kernel(const float* __restrict__ zi, const float* __restrict__ zj,
                            unsigned short* __restrict__ repsB,
                            unsigned short* __restrict__ repsA,
                            float* __restrict__ out) {
    int w = threadIdx.x >> 6;
    int lane = threadIdx.x & 63;
    int row = blockIdx.x * 4 + w;
    const float* src = (row < BHALF) ? (zi + (size_t)row * DDIM)
                                     : (zj + (size_t)(row - BHALF) * DDIM);
    float2 v = ((const float2*)src)[lane];
    float ss = v.x * v.x + v.y * v.y;
    #pragma unroll
    for (int d = 1; d < 64; d <<= 1) ss += __shfl_xor(ss, d, 64);
    float inv = 1.0f / fmaxf(sqrtf(ss), 1e-12f);
    float x = v.x * inv, y = v.y * inv;
    unsigned int pb = (unsigned int)f2bf(x) | ((unsigned int)f2bf(y) << 16);
    unsigned int pa = (unsigned int)f2bf(x * C_EXP) | ((unsigned int)f2bf(y * C_EXP) << 16);
    ((unsigned int*)repsB)[(size_t)row * (DDIM / 2) + lane] = pb;
    ((unsigned int*)repsA)[(size_t)row * (DDIM / 2) + lane] = pa;
    if (blockIdx.x == 0 && threadIdx.x == 0) out[0] = 0.0f;
}

// ---------------- K2: fused GEMM + online double-exp logsumexp ----------------
__global__ __launch_bounds__(256, 4)
void ntx_main(const unsigned short* __restrict__ repsA,
              const unsigned short* __restrict__ repsB,
              float2* __restrict__ part) {
    __shared__ unsigned short lds[TILE * LDS_STRIDE];   // 34816 B
    const int tid = threadIdx.x;
    const int w = tid >> 6, lane = tid & 63;
    const int laneLo = lane & 15, quad = lane >> 4;
    const int bx = blockIdx.x, by = blockIdx.y;
    const int rowBase = bx * TILE + w * 32;             // wave owns 32 rows

    // A fragments (scaled reps): m = lane&15, k = quad*8 + j
    bf16x8 afrag[2][4];
    #pragma unroll
    for (int rt = 0; rt < 2; ++rt)
        #pragma unroll
        for (int kt = 0; kt < 4; ++kt) {
            int r = rowBase + rt * 16 + laneLo;
            int k = kt * 32 + quad * 8;
            afrag[rt][kt] = *(const bf16x8*)(repsA + (size_t)r * DDIM + k);
        }

    // Online state per lane: rows grow[rt][rg] = rowBase + rt*16 + quad*4 + rg
    float mst[2][4], sst[2][4];
    #pragma unroll
    for (int rt = 0; rt < 2; ++rt)
        #pragma unroll
        for (int rg = 0; rg < 4; ++rg) { mst[rt][rg] = 0.0f; sst[rt][rg] = 0.0f; }

    const int colBase0 = by * COLS_PER_SPLIT;
    const uint4* repsV = (const uint4*)repsB;

    for (int it = 0; it < NITERS; ++it) {
        int colBase = colBase0 + it * TILE;
        __syncthreads();
        #pragma unroll
        for (int i = 0; i < 8; ++i) {
            int idx = tid + i * 256;
            int r = idx >> 4, c = idx & 15;
            uint4 v = repsV[(size_t)(colBase + r) * 16 + c];
            *(uint4*)(&lds[r * LDS_STRIDE + c * 8]) = v;
        }
        __syncthreads();

        f32x4 acc[2][8];
        #pragma unroll
        for (int rt = 0; rt < 2; ++rt)
            #pragma unroll
            for (int c8 = 0; c8 < 8; ++c8) acc[rt][c8] = (f32x4){0.f, 0.f, 0.f, 0.f};

        #pragma unroll
        for (int c8 = 0; c8 < 8; ++c8) {
            bf16x8 bfrag[4];
            int brow = c8 * 16 + laneLo;
            #pragma unroll
            for (int kt = 0; kt < 4; ++kt)
                bfrag[kt] = *(const bf16x8*)(&lds[brow * LDS_STRIDE + kt * 32 + quad * 8]);
            #pragma unroll
            for (int rt = 0; rt < 2; ++rt)
                #pragma unroll
                for (int kt = 0; kt < 4; ++kt)
                    acc[rt][c8] = __builtin_amdgcn_mfma_f32_16x16x32_bf16(
                        afrag[rt][kt], bfrag[kt], acc[rt][c8], 0, 0, 0);
        }

        // Epilogue: a = sim*log2e/T already. C/D: col = lane&15, row = quad*4+rg
        #pragma unroll
        for (int rt = 0; rt < 2; ++rt)
            #pragma unroll
            for (int rg = 0; rg < 4; ++rg) {
                int gr = rowBase + rt * 16 + quad * 4 + rg;
                int drel = gr - colBase - laneLo;        // diag at c8*16 == drel
                float av[8];
                #pragma unroll
                for (int c8 = 0; c8 < 8; ++c8) {
                    float x = acc[rt][c8][rg];
                    av[c8] = (drel == c8 * 16) ? -__builtin_inff() : x;
                }
                float m0 = fmaxf(av[0], av[1]), m1 = fmaxf(av[2], av[3]);
                float m2 = fmaxf(av[4], av[5]), m3 = fmaxf(av[6], av[7]);
                float lm = fmaxf(fmaxf(m0, m1), fmaxf(m2, m3));
                float em = __builtin_amdgcn_exp2f(lm);   // tile-local max e
                float mo = mst[rt][rg];
                float mn = fmaxf(mo, em);
                float mnL = mn * LOG2E;
                float s = sst[rt][rg] * __builtin_amdgcn_exp2f(fmaf(mo, LOG2E, -mnL));
                float s0 = 0.f, s1 = 0.f;
                #pragma unroll
                for (int c8 = 0; c8 < 8; c8 += 2) {
                    float e0 = __builtin_amdgcn_exp2f(av[c8]);
                    float e1 = __builtin_amdgcn_exp2f(av[c8 + 1]);
                    s0 += __builtin_amdgcn_exp2f(fmaf(e0, LOG2E, -mnL));
                    s1 += __builtin_amdgcn_exp2f(fmaf(e1, LOG2E, -mnL));
                }
                mst[rt][rg] = mn; sst[rt][rg] = s + s0 + s1;
            }
    }

    // Merge {m,s} across the 16 lanes sharing each row; write partials
    #pragma unroll
    for (int rt = 0; rt < 2; ++rt)
        #pragma unroll
        for (int rg = 0; rg < 4; ++rg) {
            float m = mst[rt][rg], s = sst[rt][rg];
            #pragma unroll
            for (int d = 1; d < 16; d <<= 1) {
                float mo = __shfl_xor(m, d, 64);
                float so = __shfl_xor(s, d, 64);
                float mn = fmaxf(m, mo);
                s = s * __builtin_amdgcn_exp2f((m - mn) * LOG2E)
                  + so * __builtin_amdgcn_exp2f((mo - mn) * LOG2E);
                m = mn;
            }
            if (laneLo == 0) {
                int gr = rowBase + rt * 16 + quad * 4 + rg;
                part[(size_t)gr * NSPLIT + by] = make_float2(m, s);
            }
        }
}

// ---------------- K3: pos via direct dot; combine splits; mean ----------------
__global__ void finish_kernel(const unsigned short* __restrict__ repsB,
                              const float2* __restrict__ part,
                              float* __restrict__ out) {
    int row = blockIdx.x * 256 + threadIdx.x;           // 64 blocks x 256
    int prow = (row < BHALF) ? row + BHALF : row - BHALF;
    const uint4* rv = (const uint4*)repsB + (size_t)row * 16;
    const uint4* pv = (const uint4*)repsB + (size_t)prow * 16;
    float dot = 0.0f;
    #pragma unroll
    for (int c = 0; c < 16; ++c) {
        uint4 a = rv[c], b = pv[c];
        dot = fmaf(bflo(a.x), bflo(b.x), dot); dot = fmaf(bfhi(a.x), bfhi(b.x), dot);
        dot = fmaf(bflo(a.y), bflo(b.y), dot); dot = fmaf(bfhi(a.y), bfhi(b.y), dot);
        dot = fmaf(bflo(a.z), bflo(b.z), dot); dot = fmaf(bfhi(a.z), bfhi(b.z), dot);
        dot = fmaf(bflo(a.w), bflo(b.w), dot); dot = fmaf(bfhi(a.w), bfhi(b.w), dot);
    }
    float pos = __builtin_amdgcn_exp2f(dot * C_EXP);    // exp(sim/T)

    float M = 0.0f;
    float2 p[NSPLIT];
    #pragma unroll
    for (int k = 0; k < NSPLIT; ++k) {
        p[k] = part[(size_t)row * NSPLIT + k];
        M = fmaxf(M, p[k].x);
    }
    float S = 0.0f;
    #pragma unroll
    for (int k = 0; k < NSPLIT; ++k)
        S += p[k].y * __builtin_amdgcn_exp2f((p[k].x - M) * LOG2E);
    float v = (M + logf(S)) - pos;                      // lse - pos

    #pragma unroll
    for (int d = 1; d < 64; d <<= 1) v += __shfl_xor(v, d, 64);
    __shared__ float red[4];
    int lane = threadIdx.x & 63, w = threadIdx.x >> 6;
    if (lane == 0) red[w] = v;
    __syncthreads();
    if (threadIdx.x == 0)
        atomicAdd(out, (red[0] + red[1] + red[2] + red[3]) * (1.0f / NROWS));
}

extern "C" void kernel_launch(void* const* d_in, const int* in_sizes, int n_in,
                              void* d_out, int out_size, void* d_ws, size_t ws_size,
                              hipStream_t stream) {
    const float* zi = (const float*)d_in[0];
    const float* zj = (const float*)d_in[1];
    float* out = (float*)d_out;
    unsigned short* repsB = (unsigned short*)d_ws;                              // 4 MiB
    unsigned short* repsA = repsB + (size_t)NROWS * DDIM;                       // 4 MiB
    float2* part = (float2*)((char*)d_ws + 2 * (size_t)NROWS * DDIM * 2);       // 1 MiB

    norm_kernel<<<NROWS / 4, 256, 0, stream>>>(zi, zj, repsB, repsA, out);
    ntx_main<<<dim3(NROWS / TILE, NSPLIT), 256, 0, stream>>>(repsA, repsB, part);
    finish_kernel<<<NROWS / 256, 256, 0, stream>>>(repsB, part, out);
}

// Round 3
// 182.882 us; speedup vs baseline: 1.5697x; 1.3722x over previous
//
#include <hip/hip_runtime.h>
#include <hip/hip_bf16.h>

// NT-Xent (B=8192, D=128), fused flash-style lse over e=exp(sim/T).
// K1: L2-normalize -> bf16 repsB[16384][128]; also repsA = repsB * (log2e/T)
//     so MFMA(A=repsA, B=repsB^T) yields a = sim*log2e/T directly; zero d_out.
// K2: grid (128 row-blocks x 8 col-splits); per 128x128 tile: MFMA -> a;
//     mask diag to -inf; online max/sum of e=exp2(a) in log2 domain with raw
//     v_exp_f32; per-(row,split) {m,s} partials.
//     launch_bounds(256,2): kernel needs ~160 unified VGPRs (64 acc + 32
//     afrag + bfrag + state); (256,4) caps at 128 -> 500 MB scratch spill (R2).
// K3: per row: pos = exp(dot/T) via direct bf16 dot; combine 8 partials;
//     mean(m + log S - pos) -> atomicAdd into d_out.

#define NROWS 16384
#define BHALF 8192
#define DDIM  128
#define TILE  128
#define NSPLIT 8
#define COLS_PER_SPLIT (NROWS / NSPLIT)   // 2048
#define NITERS (COLS_PER_SPLIT / TILE)    // 16
#define LDS_STRIDE 136                    // bf16: +8 pad, keeps 16B alignment
#define LOG2E 1.4426950408889634f
#define C_EXP (LOG2E / 0.07f)

typedef __attribute__((ext_vector_type(8))) short bf16x8;
typedef __attribute__((ext_vector_type(4))) float f32x4;

__device__ inline unsigned short f2bf(float x) {
    unsigned int b = __float_as_uint(x);
    b += 0x7FFFu + ((b >> 16) & 1u);
    return (unsigned short)(b >> 16);
}
__device__ inline float bflo(unsigned int u) { return __uint_as_float(u << 16); }
__device__ inline float bfhi(unsigned int u) { return __uint_as_float(u & 0xFFFF0000u); }

// ---------------- K1: normalize -> repsB (unit) + repsA (unit * C_EXP) ----------------
__global__ void norm_kernel(const float* __restrict__ zi, const float* __restrict__ zj,
                            unsigned short* __restrict__ repsB,
                            unsigned short* __restrict__ repsA,
                            float* __restrict__ out) {
    int w = threadIdx.x >> 6;
    int lane = threadIdx.x & 63;
    int row = blockIdx.x * 4 + w;
    const float* src = (row < BHALF) ? (zi + (size_t)row * DDIM)
                                     : (zj + (size_t)(row - BHALF) * DDIM);
    float2 v = ((const float2*)src)[lane];
    float ss = v.x * v.x + v.y * v.y;
    #pragma unroll
    for (int d = 1; d < 64; d <<= 1) ss += __shfl_xor(ss, d, 64);
    float inv = 1.0f / fmaxf(sqrtf(ss), 1e-12f);
    float x = v.x * inv, y = v.y * inv;
    unsigned int pb = (unsigned int)f2bf(x) | ((unsigned int)f2bf(y) << 16);
    unsigned int pa = (unsigned int)f2bf(x * C_EXP) | ((unsigned int)f2bf(y * C_EXP) << 16);
    ((unsigned int*)repsB)[(size_t)row * (DDIM / 2) + lane] = pb;
    ((unsigned int*)repsA)[(size_t)row * (DDIM / 2) + lane] = pa;
    if (blockIdx.x == 0 && threadIdx.x == 0) out[0] = 0.0f;
}

// ---------------- K2: fused GEMM + online double-exp logsumexp ----------------
__global__ __launch_bounds__(256, 2)
void ntx_main(const unsigned short* __restrict__ repsA,
              const unsigned short* __restrict__ repsB,
              float2* __restrict__ part) {
    __shared__ unsigned short lds[TILE * LDS_STRIDE];   // 34816 B
    const int tid = threadIdx.x;
    const int w = tid >> 6, lane = tid & 63;
    const int laneLo = lane & 15, quad = lane >> 4;
    const int bx = blockIdx.x, by = blockIdx.y;
    const int rowBase = bx * TILE + w * 32;             // wave owns 32 rows

    // A fragments (scaled reps): m = lane&15, k = quad*8 + j
    bf16x8 afrag[2][4];
    #pragma unroll
    for (int rt = 0; rt < 2; ++rt)
        #pragma unroll
        for (int kt = 0; kt < 4; ++kt) {
            int r = rowBase + rt * 16 + laneLo;
            int k = kt * 32 + quad * 8;
            afrag[rt][kt] = *(const bf16x8*)(repsA + (size_t)r * DDIM + k);
        }

    // Online state per lane: rows grow[rt][rg] = rowBase + rt*16 + quad*4 + rg
    float mst[2][4], sst[2][4];
    #pragma unroll
    for (int rt = 0; rt < 2; ++rt)
        #pragma unroll
        for (int rg = 0; rg < 4; ++rg) { mst[rt][rg] = 0.0f; sst[rt][rg] = 0.0f; }

    const int colBase0 = by * COLS_PER_SPLIT;
    const uint4* repsV = (const uint4*)repsB;

    for (int it = 0; it < NITERS; ++it) {
        int colBase = colBase0 + it * TILE;
        __syncthreads();
        #pragma unroll
        for (int i = 0; i < 8; ++i) {
            int idx = tid + i * 256;
            int r = idx >> 4, c = idx & 15;
            uint4 v = repsV[(size_t)(colBase + r) * 16 + c];
            *(uint4*)(&lds[r * LDS_STRIDE + c * 8]) = v;
        }
        __syncthreads();

        f32x4 acc[2][8];
        #pragma unroll
        for (int rt = 0; rt < 2; ++rt)
            #pragma unroll
            for (int c8 = 0; c8 < 8; ++c8) acc[rt][c8] = (f32x4){0.f, 0.f, 0.f, 0.f};

        #pragma unroll
        for (int c8 = 0; c8 < 8; ++c8) {
            bf16x8 bfrag[4];
            int brow = c8 * 16 + laneLo;
            #pragma unroll
            for (int kt = 0; kt < 4; ++kt)
                bfrag[kt] = *(const bf16x8*)(&lds[brow * LDS_STRIDE + kt * 32 + quad * 8]);
            #pragma unroll
            for (int rt = 0; rt < 2; ++rt)
                #pragma unroll
                for (int kt = 0; kt < 4; ++kt)
                    acc[rt][c8] = __builtin_amdgcn_mfma_f32_16x16x32_bf16(
                        afrag[rt][kt], bfrag[kt], acc[rt][c8], 0, 0, 0);
        }

        // Epilogue: a = sim*log2e/T already. C/D: col = lane&15, row = quad*4+rg
        #pragma unroll
        for (int rt = 0; rt < 2; ++rt)
            #pragma unroll
            for (int rg = 0; rg < 4; ++rg) {
                int gr = rowBase + rt * 16 + quad * 4 + rg;
                int drel = gr - colBase - laneLo;        // diag at c8*16 == drel
                float av[8];
                #pragma unroll
                for (int c8 = 0; c8 < 8; ++c8) {
                    float x = acc[rt][c8][rg];
                    av[c8] = (drel == c8 * 16) ? -__builtin_inff() : x;
                }
                float m0 = fmaxf(av[0], av[1]), m1 = fmaxf(av[2], av[3]);
                float m2 = fmaxf(av[4], av[5]), m3 = fmaxf(av[6], av[7]);
                float lm = fmaxf(fmaxf(m0, m1), fmaxf(m2, m3));
                float em = __builtin_amdgcn_exp2f(lm);   // tile-local max e
                float mo = mst[rt][rg];
                float mn = fmaxf(mo, em);
                float mnL = mn * LOG2E;
                float s = sst[rt][rg] * __builtin_amdgcn_exp2f(fmaf(mo, LOG2E, -mnL));
                float s0 = 0.f, s1 = 0.f;
                #pragma unroll
                for (int c8 = 0; c8 < 8; c8 += 2) {
                    float e0 = __builtin_amdgcn_exp2f(av[c8]);
                    float e1 = __builtin_amdgcn_exp2f(av[c8 + 1]);
                    s0 += __builtin_amdgcn_exp2f(fmaf(e0, LOG2E, -mnL));
                    s1 += __builtin_amdgcn_exp2f(fmaf(e1, LOG2E, -mnL));
                }
                mst[rt][rg] = mn; sst[rt][rg] = s + s0 + s1;
            }
    }

    // Merge {m,s} across the 16 lanes sharing each row; write partials
    #pragma unroll
    for (int rt = 0; rt < 2; ++rt)
        #pragma unroll
        for (int rg = 0; rg < 4; ++rg) {
            float m = mst[rt][rg], s = sst[rt][rg];
            #pragma unroll
            for (int d = 1; d < 16; d <<= 1) {
                float mo = __shfl_xor(m, d, 64);
                float so = __shfl_xor(s, d, 64);
                float mn = fmaxf(m, mo);
                s = s * __builtin_amdgcn_exp2f((m - mn) * LOG2E)
                  + so * __builtin_amdgcn_exp2f((mo - mn) * LOG2E);
                m = mn;
            }
            if (laneLo == 0) {
                int gr = rowBase + rt * 16 + quad * 4 + rg;
                part[(size_t)gr * NSPLIT + by] = make_float2(m, s);
            }
        }
}

// ---------------- K3: pos via direct dot; combine splits; mean ----------------
__global__ void finish_kernel(const unsigned short* __restrict__ repsB,
                              const float2* __restrict__ part,
                              float* __restrict__ out) {
    int row = blockIdx.x * 256 + threadIdx.x;           // 64 blocks x 256
    int prow = (row < BHALF) ? row + BHALF : row - BHALF;
    const uint4* rv = (const uint4*)repsB + (size_t)row * 16;
    const uint4* pv = (const uint4*)repsB + (size_t)prow * 16;
    float dot = 0.0f;
    #pragma unroll
    for (int c = 0; c < 16; ++c) {
        uint4 a = rv[c], b = pv[c];
        dot = fmaf(bflo(a.x), bflo(b.x), dot); dot = fmaf(bfhi(a.x), bfhi(b.x), dot);
        dot = fmaf(bflo(a.y), bflo(b.y), dot); dot = fmaf(bfhi(a.y), bfhi(b.y), dot);
        dot = fmaf(bflo(a.z), bflo(b.z), dot); dot = fmaf(bfhi(a.z), bfhi(b.z), dot);
        dot = fmaf(bflo(a.w), bflo(b.w), dot); dot = fmaf(bfhi(a.w), bfhi(b.w), dot);
    }
    float pos = __builtin_amdgcn_exp2f(dot * C_EXP);    // exp(sim/T)

    float M = 0.0f;
    float2 p[NSPLIT];
    #pragma unroll
    for (int k = 0; k < NSPLIT; ++k) {
        p[k] = part[(size_t)row * NSPLIT + k];
        M = fmaxf(M, p[k].x);
    }
    float S = 0.0f;
    #pragma unroll
    for (int k = 0; k < NSPLIT; ++k)
        S += p[k].y * __builtin_amdgcn_exp2f((p[k].x - M) * LOG2E);
    float v = (M + logf(S)) - pos;                      // lse - pos

    #pragma unroll
    for (int d = 1; d < 64; d <<= 1) v += __shfl_xor(v, d, 64);
    __shared__ float red[4];
    int lane = threadIdx.x & 63, w = threadIdx.x >> 6;
    if (lane == 0) red[w] = v;
    __syncthreads();
    if (threadIdx.x == 0)
        atomicAdd(out, (red[0] + red[1] + red[2] + red[3]) * (1.0f / NROWS));
}

extern "C" void kernel_launch(void* const* d_in, const int* in_sizes, int n_in,
                              void* d_out, int out_size, void* d_ws, size_t ws_size,
                              hipStream_t stream) {
    const float* zi = (const float*)d_in[0];
    const float* zj = (const float*)d_in[1];
    float* out = (float*)d_out;
    unsigned short* repsB = (unsigned short*)d_ws;                              // 4 MiB
    unsigned short* repsA = repsB + (size_t)NROWS * DDIM;                       // 4 MiB
    float2* part = (float2*)((char*)d_ws + 2 * (size_t)NROWS * DDIM * 2);       // 1 MiB

    norm_kernel<<<NROWS / 4, 256, 0, stream>>>(zi, zj, repsB, repsA, out);
    ntx_main<<<dim3(NROWS / TILE, NSPLIT), 256, 0, stream>>>(repsA, repsB, part);
    finish_kernel<<<NROWS / 256, 256, 0, stream>>>(repsB, part, out);
}